// Round 9
// baseline (35.316 us; speedup 1.0000x reference)
//
#include <hip/hip_runtime.h>
#include <cstdint>
#include <climits>

#define GRID_N 16777216
#define GMAX (GRID_N - 1)
#define N_STEPS 100
#define NCAND (2 * N_STEPS + 1)   // 200 boundary-origin candidates + c0
#define NNODE (2 * N_STEPS)       // boundary-state nodes (t,b), t in [0,100)
#define NLEV 8                    // 2^7 = 128 >= 100 transitions
#define NBLK 2048
#define THREADS 256
#define TTOT (NBLK * THREADS)     // 524288 threads; GRID_N/2 = 16*TTOT float4s

#define TERM_FLAG 0x40000000      // terminal: t==100, low 24 bits = final c
#define FALLBACK  (-1)

// ws layout: [0, 16K): partials (2048 f64); [16K, 16K+201*16): candidate gather
#define GATH_OFF 16384

// nan_to_num(psi, nan=0.0, posinf=1.0, neginf=-1.0)
__device__ __forceinline__ float fixv(float v) {
    if (isnan(v)) return 0.0f;
    if (isinf(v)) return v > 0.0f ? 1.0f : -1.0f;
    return v;
}

// psi0*psi0 + psi1*psi1 in strict f32, no FMA contraction (match host semantics)
__device__ __forceinline__ float raw_prob(float a, float b) {
    return __fadd_rn(__fmul_rn(a, a), __fmul_rn(b, b));
}

// x86 cvttss2si semantics: out-of-range or NaN -> INT_MIN (NOT GPU saturation)
__device__ __forceinline__ int host_f2i(float sf) {
    if (!(sf >= -2147483648.0f && sf < 2147483648.0f)) return INT_MIN;
    return (int)sf;
}

__device__ __forceinline__ int wrap_clip(int c, int shift) {
    int r = (int)((unsigned)c + (unsigned)shift);  // int32 wrapping add (XLA/NumPy)
    if (r < 0) r = 0;
    if (r > GMAX) r = GMAX;
    return r;
}

__device__ __forceinline__ double pair_prob(float4 v) {
    return (double)raw_prob(fixv(v.x), fixv(v.y)) +
           (double)raw_prob(fixv(v.z), fixv(v.w));
}

// candidate position at boundary-origin node tid (exact walk-step fp with s==0)
__device__ __forceinline__ int cand_pos(int tid, const float* noise,
                                        const int* c0p, float DXf, float DTf,
                                        float SQ2DTf) {
    if (tid == NCAND - 1) return *c0p;
    int t = tid >> 1;
    float n = noise[t];
    float move = __fadd_rn(__fmul_rn(0.0f, DTf), __fmul_rn(n, SQ2DTf));
    if (!isfinite(move)) move = 0.0f;
    int shift = host_f2i(__fdiv_rn(move, DXf));
    int b = (tid & 1) ? GMAX : 0;
    return wrap_clip(b, shift);
}

__global__ __launch_bounds__(256) void qpe_sum_kernel(const float4* __restrict__ psi4,
                                                      double* __restrict__ partials,
                                                      const float* __restrict__ psi,
                                                      const float* __restrict__ noise,
                                                      const int* __restrict__ c0p,
                                                      float4* __restrict__ gath) {
    const int tid = threadIdx.x;
    const int bid = blockIdx.x;

    if (bid == NBLK) {
        // ---- gather block: scattered candidate loads, runs concurrent w/ sum ----
        const float DXf    = (float)(20.0 / (double)(GRID_N - 1));
        const float DTf    = 0.01f;
        const float SQ2DTf = (float)0.14142135623730950488;
        if (tid < NCAND) {
            int myc = cand_pos(tid, noise, c0p, DXf, DTf, SQ2DTf);
            float4 g = make_float4(0.0f, 0.0f, 0.0f, 0.0f);
            if (myc > 0 && myc < GMAX) {
                float2 lo = *(const float2*)(psi + 2 * myc - 2);  // psi[c-1]
                float2 hi = *(const float2*)(psi + 2 * myc + 2);  // psi[c+1]
                g = make_float4(lo.x, lo.y, hi.x, hi.y);
            }
            gath[tid] = g;
        }
        return;
    }

    // ---- sum slice `bid`: 8 independent loads in flight (deep MLP) ----
    int i = bid * THREADS + tid;
    double a0 = 0.0, a1 = 0.0, a2 = 0.0, a3 = 0.0;
    double a4 = 0.0, a5 = 0.0, a6 = 0.0, a7 = 0.0;
#pragma unroll
    for (int k = 0; k < 2; ++k) {
        float4 v0 = psi4[i];
        float4 v1 = psi4[i + TTOT];
        float4 v2 = psi4[i + 2 * TTOT];
        float4 v3 = psi4[i + 3 * TTOT];
        float4 v4 = psi4[i + 4 * TTOT];
        float4 v5 = psi4[i + 5 * TTOT];
        float4 v6 = psi4[i + 6 * TTOT];
        float4 v7 = psi4[i + 7 * TTOT];
        i += 8 * TTOT;
        a0 += pair_prob(v0);
        a1 += pair_prob(v1);
        a2 += pair_prob(v2);
        a3 += pair_prob(v3);
        a4 += pair_prob(v4);
        a5 += pair_prob(v5);
        a6 += pair_prob(v6);
        a7 += pair_prob(v7);
    }
    double acc = ((a0 + a1) + (a2 + a3)) + ((a4 + a5) + (a6 + a7));
    __shared__ double sm[256];
    sm[tid] = acc;
    __syncthreads();
    for (int s = 128; s > 0; s >>= 1) {   // fixed-order tree -> deterministic
        if (tid < s) sm[tid] += sm[tid + s];
        __syncthreads();
    }
    if (tid == 0) partials[bid] = sm[0];
}

__global__ __launch_bounds__(256) void qpe_walk_kernel(const float* __restrict__ psi,
                                                       const float* __restrict__ noise,
                                                       const float* __restrict__ x,
                                                       const int* __restrict__ c0p,
                                                       const double* __restrict__ partials,
                                                       const float4* __restrict__ gath,
                                                       float* __restrict__ out) {
    const int tid = threadIdx.x;
    const float DXf    = (float)(20.0 / (double)(GRID_N - 1));
    const float TWODXf = (float)(2.0 * (20.0 / (double)(GRID_N - 1)));
    const float DTf    = 0.01f;
    const float SQ2DTf = (float)0.14142135623730950488;  // np.sqrt(0.02) -> f32

    __shared__ int    cand_c[256];
    __shared__ int    cand_next[256];
    __shared__ int    lift[NLEV][NNODE];
    __shared__ double red[256];
    __shared__ float  norm_sh;

    // ---- phase A: candidate positions (recomputed, exact) + gathered psi ----
    int myc = -1;
    float4 g = make_float4(0.0f, 0.0f, 0.0f, 0.0f);
    if (tid < NCAND) {
        myc = cand_pos(tid, noise, c0p, DXf, DTf, SQ2DTf);
        g = gath[tid];   // one coalesced 16B load (pre-gathered by sum kernel)
        asm volatile("" : "+v"(g.x), "+v"(g.y), "+v"(g.z), "+v"(g.w));
    }

    // ---- phase B: deterministic fixed-order f64 reduce of partials ----
    double acc = 0.0;
#pragma unroll
    for (int k = 0; k < NBLK / 256; ++k) acc += partials[tid + k * 256];
    red[tid] = acc;
    __syncthreads();
    for (int s = 128; s > 0; s >>= 1) {
        if (tid < s) red[tid] += red[tid + s];
        __syncthreads();
    }
    if (tid == 0) {
        float S = (float)red[0];
        norm_sh = __fadd_rn(__fmul_rn(S, DXf), 1e-8f);
    }
    __syncthreads();
    float norm = norm_sh;

    // ---- phase C: per-candidate score AND precomputed next position ----
    float s_val = 0.0f;
    int nxt = -2;   // sentinel: no precomputed next
    if (tid < NCAND && myc > 0 && myc < GMAX) {
        float a0 = fixv(g.x), b0 = fixv(g.y);
        float a1 = fixv(g.z), b1 = fixv(g.w);
        float p1 = fmaxf(__fdiv_rn(raw_prob(a1, b1), norm), 1e-12f);
        float p0 = fmaxf(__fdiv_rn(raw_prob(a0, b0), norm), 1e-12f);
        s_val = __fdiv_rn(__fsub_rn(logf(p1), logf(p0)), TWODXf);
        // candidate tid is occupied at step (tid>>1)+1 (boundary-origin) or 0 (c0)
        int nidx = (tid == NCAND - 1) ? 0 : (tid >> 1) + 1;
        if (nidx < N_STEPS) {
            float n = noise[nidx];
            // exact walk-step fp sequence with s = s_val:
            float move = __fadd_rn(__fmul_rn(s_val, DTf), __fmul_rn(n, SQ2DTf));
            if (!isfinite(move)) move = 0.0f;
            int shift = host_f2i(__fdiv_rn(move, DXf));
            nxt = wrap_clip(myc, shift);
        }
    }
    cand_c[tid] = (tid < NCAND) ? myc : -1;
    cand_next[tid] = nxt;
    // warm x[] at possible final positions (prefetch; values discarded)
    if (tid < NCAND) {
        float w = x[myc < 0 ? 0 : myc];
        float w2 = x[(nxt < 0) ? 0 : nxt];
        asm volatile("" :: "v"(w), "v"(w2));
    }
    __syncthreads();

    // ---- phase L0: level-0 transitions for boundary nodes (t,b), n = 2t+b ----
    if (tid < NNODE) {
        int t = tid >> 1;
        int v;
        int c1 = cand_c[tid];                    // landing after step t (exact)
        if (c1 == 0 || c1 == GMAX) {
            int t1 = t + 1;
            v = (t1 == N_STEPS) ? (TERM_FLAG | c1) : ((t1 << 1) | (c1 == GMAX));
        } else if (t + 1 == N_STEPS) {
            v = TERM_FLAG | c1;                  // interior final at t=100
        } else {
            int c2 = cand_next[tid];             // position after step t+1 (exact)
            if (c2 == 0 || c2 == GMAX) {
                int t2 = t + 2;
                v = (t2 == N_STEPS) ? (TERM_FLAG | c2) : ((t2 << 1) | (c2 == GMAX));
            } else if (t + 2 == N_STEPS) {
                v = TERM_FLAG | c2;              // interior final at t=100
            } else {
                v = FALLBACK;                    // interior non-candidate mid-walk
            }
        }
        lift[0][tid] = v;
    }
    __syncthreads();
    // ---- doubling levels: lift[k][n] = lift[k-1] applied twice (saturating) ----
#pragma unroll
    for (int k = 1; k < NLEV; ++k) {
        if (tid < NNODE) {
            int v = lift[k - 1][tid];
            lift[k][tid] = (v >= 0 && v < TERM_FLAG) ? lift[k - 1][v] : v;
        }
        __syncthreads();
    }

    if (tid != 0) return;

    // ---- phase D: traverse ----
    int c = cand_c[NCAND - 1];   // == *c0p
    int t = 0;
    bool need_serial = false;

    // step 0 from c0 (interior in this problem; handle boundary anyway)
    int node;
    if (c == 0 || c == GMAX) {
        node = (0 << 1) | (c == GMAX);
    } else {
        int n1 = cand_next[NCAND - 1];           // position after step 0 (exact)
        if (n1 == -2) { need_serial = true; node = -1; }
        else if (n1 == 0 || n1 == GMAX) {
            if (N_STEPS == 1) { out[0] = x[n1]; return; }
            node = (1 << 1) | (n1 == GMAX);
        } else if (N_STEPS == 1) {
            out[0] = x[n1]; return;
        } else {
            need_serial = true; t = 1; c = n1; node = -1;   // rare
        }
    }

    if (!need_serial) {
        // binary lifting: highest level covers 128 >= 100 transitions, so one
        // application usually terminates; descend on fallback-blocked levels.
        for (int guard = 0; guard < 64; ++guard) {
            if (node >= TERM_FLAG) break;
            int applied = 0;
            for (int k = NLEV - 1; k >= 0; --k) {
                int v = lift[k][node];
                if (v != FALLBACK) {
                    node = v;
                    applied = 1;
                    break;
                }
            }
            if (!applied) {                       // lift[0][node] == FALLBACK
                t = node >> 1;
                c = (node & 1) ? GMAX : 0;
                need_serial = true;
                break;
            }
            if (node >= TERM_FLAG) break;
        }
        if (!need_serial && node >= TERM_FLAG) {
            out[0] = x[node & 0xFFFFFF];
            return;
        }
    }

    // ---- serial fallback from exact state (t, c): r6 loop, unconditional ----
    while (t < N_STEPS) {
        if (c <= 0 || c >= GMAX) {
            int j = 2 * t + ((c != 0) ? 1 : 0);
            c = cand_c[j];                        // exact landing (phase A)
            ++t;
        } else {
            float a1v = fixv(psi[2 * (c + 1)]);
            float b1v = fixv(psi[2 * (c + 1) + 1]);
            float a0v = fixv(psi[2 * (c - 1)]);
            float b0v = fixv(psi[2 * (c - 1) + 1]);
            float p1 = fmaxf(__fdiv_rn(raw_prob(a1v, b1v), norm), 1e-12f);
            float p0 = fmaxf(__fdiv_rn(raw_prob(a0v, b0v), norm), 1e-12f);
            float s = __fdiv_rn(__fsub_rn(logf(p1), logf(p0)), TWODXf);
            float n = noise[t];
            float move = __fadd_rn(__fmul_rn(s, DTf), __fmul_rn(n, SQ2DTf));
            if (!isfinite(move)) move = 0.0f;
            int shift = host_f2i(__fdiv_rn(move, DXf));
            c = wrap_clip(c, shift);
            ++t;
        }
    }
    out[0] = x[c];
}

extern "C" void kernel_launch(void* const* d_in, const int* in_sizes, int n_in,
                              void* d_out, int out_size, void* d_ws, size_t ws_size,
                              hipStream_t stream) {
    const float* psi   = (const float*)d_in[0];
    const float* noise = (const float*)d_in[1];
    const float* x     = (const float*)d_in[2];
    const int*   c0    = (const int*)d_in[3];
    float* out = (float*)d_out;

    double* partials = (double*)d_ws;
    float4* gath = (float4*)((char*)d_ws + GATH_OFF);

    qpe_sum_kernel<<<NBLK + 1, THREADS, 0, stream>>>((const float4*)psi, partials,
                                                     psi, noise, c0, gath);
    qpe_walk_kernel<<<1, THREADS, 0, stream>>>(psi, noise, x, c0, partials,
                                               gath, out);
}

// Round 10
// 31.654 us; speedup vs baseline: 1.1157x; 1.1157x over previous
//
#include <hip/hip_runtime.h>
#include <cstdint>
#include <climits>

#define GRID_N 16777216
#define GMAX (GRID_N - 1)
#define N_STEPS 100
#define NCAND (2 * N_STEPS + 1)   // 200 boundary-origin candidates + c0
#define NNODE (2 * N_STEPS)       // boundary-state nodes (t,b), t in [0,100)
#define NLEV 8                    // 2^7 = 128 >= 100 transitions
#define NBLK 2048
#define THREADS 256
#define PER_BLK (GRID_N / 2 / NBLK)   // 4096 float4s = 64KB contiguous per block

#define TERM_FLAG 0x40000000      // terminal: t==100, low 24 bits = final c
#define FALLBACK  (-1)

// ws layout: [0, 16K): partials (2048 f64); [16K, 16K+201*16): candidate gather
#define GATH_OFF 16384

// nan_to_num(psi, nan=0.0, posinf=1.0, neginf=-1.0)
__device__ __forceinline__ float fixv(float v) {
    if (isnan(v)) return 0.0f;
    if (isinf(v)) return v > 0.0f ? 1.0f : -1.0f;
    return v;
}

// psi0*psi0 + psi1*psi1 in strict f32, no FMA contraction (match host semantics)
__device__ __forceinline__ float raw_prob(float a, float b) {
    return __fadd_rn(__fmul_rn(a, a), __fmul_rn(b, b));
}

// x86 cvttss2si semantics: out-of-range or NaN -> INT_MIN (NOT GPU saturation)
__device__ __forceinline__ int host_f2i(float sf) {
    if (!(sf >= -2147483648.0f && sf < 2147483648.0f)) return INT_MIN;
    return (int)sf;
}

__device__ __forceinline__ int wrap_clip(int c, int shift) {
    int r = (int)((unsigned)c + (unsigned)shift);  // int32 wrapping add (XLA/NumPy)
    if (r < 0) r = 0;
    if (r > GMAX) r = GMAX;
    return r;
}

__device__ __forceinline__ double pair_prob(float4 v) {
    return (double)raw_prob(fixv(v.x), fixv(v.y)) +
           (double)raw_prob(fixv(v.z), fixv(v.w));
}

// candidate position at boundary-origin node tid (exact walk-step fp with s==0)
__device__ __forceinline__ int cand_pos(int tid, const float* noise,
                                        const int* c0p, float DXf, float DTf,
                                        float SQ2DTf) {
    if (tid == NCAND - 1) return *c0p;
    int t = tid >> 1;
    float n = noise[t];
    float move = __fadd_rn(__fmul_rn(0.0f, DTf), __fmul_rn(n, SQ2DTf));
    if (!isfinite(move)) move = 0.0f;
    int shift = host_f2i(__fdiv_rn(move, DXf));
    int b = (tid & 1) ? GMAX : 0;
    return wrap_clip(b, shift);
}

__global__ __launch_bounds__(256) void qpe_sum_kernel(const float4* __restrict__ psi4,
                                                      double* __restrict__ partials,
                                                      const float* __restrict__ psi,
                                                      const float* __restrict__ noise,
                                                      const int* __restrict__ c0p,
                                                      float4* __restrict__ gath) {
    const int tid = threadIdx.x;
    const int bid = blockIdx.x;

    if (bid == NBLK) {
        // ---- gather block: scattered candidate loads, runs concurrent w/ sum ----
        const float DXf    = (float)(20.0 / (double)(GRID_N - 1));
        const float DTf    = 0.01f;
        const float SQ2DTf = (float)0.14142135623730950488;
        if (tid < NCAND) {
            int myc = cand_pos(tid, noise, c0p, DXf, DTf, SQ2DTf);
            float4 g = make_float4(0.0f, 0.0f, 0.0f, 0.0f);
            if (myc > 0 && myc < GMAX) {
                float2 lo = *(const float2*)(psi + 2 * myc - 2);  // psi[c-1]
                float2 hi = *(const float2*)(psi + 2 * myc + 2);  // psi[c+1]
                g = make_float4(lo.x, lo.y, hi.x, hi.y);
            }
            gath[tid] = g;
        }
        return;
    }

    // ---- sum: CONTIGUOUS 64KB slice per block, 8 loads in flight ----
    const int base = bid * PER_BLK + tid;
    double a0 = 0.0, a1 = 0.0, a2 = 0.0, a3 = 0.0;
    double a4 = 0.0, a5 = 0.0, a6 = 0.0, a7 = 0.0;
#pragma unroll
    for (int k = 0; k < PER_BLK / (8 * THREADS); ++k) {   // 2 iterations
        const int i = base + k * 8 * THREADS;
        float4 v0 = psi4[i];
        float4 v1 = psi4[i + THREADS];
        float4 v2 = psi4[i + 2 * THREADS];
        float4 v3 = psi4[i + 3 * THREADS];
        float4 v4 = psi4[i + 4 * THREADS];
        float4 v5 = psi4[i + 5 * THREADS];
        float4 v6 = psi4[i + 6 * THREADS];
        float4 v7 = psi4[i + 7 * THREADS];
        a0 += pair_prob(v0);
        a1 += pair_prob(v1);
        a2 += pair_prob(v2);
        a3 += pair_prob(v3);
        a4 += pair_prob(v4);
        a5 += pair_prob(v5);
        a6 += pair_prob(v6);
        a7 += pair_prob(v7);
    }
    double acc = ((a0 + a1) + (a2 + a3)) + ((a4 + a5) + (a6 + a7));
    __shared__ double sm[256];
    sm[tid] = acc;
    __syncthreads();
    for (int s = 128; s > 0; s >>= 1) {   // fixed-order tree -> deterministic
        if (tid < s) sm[tid] += sm[tid + s];
        __syncthreads();
    }
    if (tid == 0) partials[bid] = sm[0];
}

__global__ __launch_bounds__(256) void qpe_walk_kernel(const float* __restrict__ psi,
                                                       const float* __restrict__ noise,
                                                       const float* __restrict__ x,
                                                       const int* __restrict__ c0p,
                                                       const double* __restrict__ partials,
                                                       const float4* __restrict__ gath,
                                                       float* __restrict__ out) {
    const int tid = threadIdx.x;
    const float DXf    = (float)(20.0 / (double)(GRID_N - 1));
    const float TWODXf = (float)(2.0 * (20.0 / (double)(GRID_N - 1)));
    const float DTf    = 0.01f;
    const float SQ2DTf = (float)0.14142135623730950488;  // np.sqrt(0.02) -> f32

    __shared__ int    cand_c[256];
    __shared__ int    cand_next[256];
    __shared__ int    lift[NLEV][NNODE];
    __shared__ double red[256];
    __shared__ float  norm_sh;

    // ---- phase A: candidate positions (recomputed, exact) + gathered psi ----
    int myc = -1;
    float4 g = make_float4(0.0f, 0.0f, 0.0f, 0.0f);
    if (tid < NCAND) {
        myc = cand_pos(tid, noise, c0p, DXf, DTf, SQ2DTf);
        g = gath[tid];   // one coalesced 16B load (pre-gathered by sum kernel)
        asm volatile("" : "+v"(g.x), "+v"(g.y), "+v"(g.z), "+v"(g.w));
    }

    // ---- phase B: deterministic fixed-order f64 reduce of partials ----
    double acc = 0.0;
#pragma unroll
    for (int k = 0; k < NBLK / 256; ++k) acc += partials[tid + k * 256];
    red[tid] = acc;
    __syncthreads();
    for (int s = 128; s > 0; s >>= 1) {
        if (tid < s) red[tid] += red[tid + s];
        __syncthreads();
    }
    if (tid == 0) {
        float S = (float)red[0];
        norm_sh = __fadd_rn(__fmul_rn(S, DXf), 1e-8f);
    }
    __syncthreads();
    float norm = norm_sh;

    // ---- phase C: per-candidate score AND precomputed next position ----
    float s_val = 0.0f;
    int nxt = -2;   // sentinel: no precomputed next
    if (tid < NCAND && myc > 0 && myc < GMAX) {
        float a0 = fixv(g.x), b0 = fixv(g.y);
        float a1 = fixv(g.z), b1 = fixv(g.w);
        float p1 = fmaxf(__fdiv_rn(raw_prob(a1, b1), norm), 1e-12f);
        float p0 = fmaxf(__fdiv_rn(raw_prob(a0, b0), norm), 1e-12f);
        s_val = __fdiv_rn(__fsub_rn(logf(p1), logf(p0)), TWODXf);
        // candidate tid is occupied at step (tid>>1)+1 (boundary-origin) or 0 (c0)
        int nidx = (tid == NCAND - 1) ? 0 : (tid >> 1) + 1;
        if (nidx < N_STEPS) {
            float n = noise[nidx];
            // exact walk-step fp sequence with s = s_val:
            float move = __fadd_rn(__fmul_rn(s_val, DTf), __fmul_rn(n, SQ2DTf));
            if (!isfinite(move)) move = 0.0f;
            int shift = host_f2i(__fdiv_rn(move, DXf));
            nxt = wrap_clip(myc, shift);
        }
    }
    cand_c[tid] = (tid < NCAND) ? myc : -1;
    cand_next[tid] = nxt;
    // warm x[] at possible final positions (prefetch; values discarded)
    if (tid < NCAND) {
        float w = x[myc < 0 ? 0 : myc];
        float w2 = x[(nxt < 0) ? 0 : nxt];
        asm volatile("" :: "v"(w), "v"(w2));
    }
    __syncthreads();

    // ---- phase L0: level-0 transitions for boundary nodes (t,b), n = 2t+b ----
    if (tid < NNODE) {
        int t = tid >> 1;
        int v;
        int c1 = cand_c[tid];                    // landing after step t (exact)
        if (c1 == 0 || c1 == GMAX) {
            int t1 = t + 1;
            v = (t1 == N_STEPS) ? (TERM_FLAG | c1) : ((t1 << 1) | (c1 == GMAX));
        } else if (t + 1 == N_STEPS) {
            v = TERM_FLAG | c1;                  // interior final at t=100
        } else {
            int c2 = cand_next[tid];             // position after step t+1 (exact)
            if (c2 == 0 || c2 == GMAX) {
                int t2 = t + 2;
                v = (t2 == N_STEPS) ? (TERM_FLAG | c2) : ((t2 << 1) | (c2 == GMAX));
            } else if (t + 2 == N_STEPS) {
                v = TERM_FLAG | c2;              // interior final at t=100
            } else {
                v = FALLBACK;                    // interior non-candidate mid-walk
            }
        }
        lift[0][tid] = v;
    }
    __syncthreads();
    // ---- doubling levels: lift[k][n] = lift[k-1] applied twice (saturating) ----
#pragma unroll
    for (int k = 1; k < NLEV; ++k) {
        if (tid < NNODE) {
            int v = lift[k - 1][tid];
            lift[k][tid] = (v >= 0 && v < TERM_FLAG) ? lift[k - 1][v] : v;
        }
        __syncthreads();
    }

    if (tid != 0) return;

    // ---- phase D: traverse ----
    int c = cand_c[NCAND - 1];   // == *c0p
    int t = 0;
    bool need_serial = false;

    // step 0 from c0 (interior in this problem; handle boundary anyway)
    int node;
    if (c == 0 || c == GMAX) {
        node = (0 << 1) | (c == GMAX);
    } else {
        int n1 = cand_next[NCAND - 1];           // position after step 0 (exact)
        if (n1 == -2) { need_serial = true; node = -1; }
        else if (n1 == 0 || n1 == GMAX) {
            if (N_STEPS == 1) { out[0] = x[n1]; return; }
            node = (1 << 1) | (n1 == GMAX);
        } else if (N_STEPS == 1) {
            out[0] = x[n1]; return;
        } else {
            need_serial = true; t = 1; c = n1; node = -1;   // rare
        }
    }

    if (!need_serial) {
        // binary lifting: highest level covers 128 >= 100 transitions, so one
        // application usually terminates; descend on fallback-blocked levels.
        for (int guard = 0; guard < 64; ++guard) {
            if (node >= TERM_FLAG) break;
            int applied = 0;
            for (int k = NLEV - 1; k >= 0; --k) {
                int v = lift[k][node];
                if (v != FALLBACK) {
                    node = v;
                    applied = 1;
                    break;
                }
            }
            if (!applied) {                       // lift[0][node] == FALLBACK
                t = node >> 1;
                c = (node & 1) ? GMAX : 0;
                need_serial = true;
                break;
            }
            if (node >= TERM_FLAG) break;
        }
        if (!need_serial && node >= TERM_FLAG) {
            out[0] = x[node & 0xFFFFFF];
            return;
        }
    }

    // ---- serial fallback from exact state (t, c): r6 loop, unconditional ----
    while (t < N_STEPS) {
        if (c <= 0 || c >= GMAX) {
            int j = 2 * t + ((c != 0) ? 1 : 0);
            c = cand_c[j];                        // exact landing (phase A)
            ++t;
        } else {
            float a1v = fixv(psi[2 * (c + 1)]);
            float b1v = fixv(psi[2 * (c + 1) + 1]);
            float a0v = fixv(psi[2 * (c - 1)]);
            float b0v = fixv(psi[2 * (c - 1) + 1]);
            float p1 = fmaxf(__fdiv_rn(raw_prob(a1v, b1v), norm), 1e-12f);
            float p0 = fmaxf(__fdiv_rn(raw_prob(a0v, b0v), norm), 1e-12f);
            float s = __fdiv_rn(__fsub_rn(logf(p1), logf(p0)), TWODXf);
            float n = noise[t];
            float move = __fadd_rn(__fmul_rn(s, DTf), __fmul_rn(n, SQ2DTf));
            if (!isfinite(move)) move = 0.0f;
            int shift = host_f2i(__fdiv_rn(move, DXf));
            c = wrap_clip(c, shift);
            ++t;
        }
    }
    out[0] = x[c];
}

extern "C" void kernel_launch(void* const* d_in, const int* in_sizes, int n_in,
                              void* d_out, int out_size, void* d_ws, size_t ws_size,
                              hipStream_t stream) {
    const float* psi   = (const float*)d_in[0];
    const float* noise = (const float*)d_in[1];
    const float* x     = (const float*)d_in[2];
    const int*   c0    = (const int*)d_in[3];
    float* out = (float*)d_out;

    double* partials = (double*)d_ws;
    float4* gath = (float4*)((char*)d_ws + GATH_OFF);

    qpe_sum_kernel<<<NBLK + 1, THREADS, 0, stream>>>((const float4*)psi, partials,
                                                     psi, noise, c0, gath);
    qpe_walk_kernel<<<1, THREADS, 0, stream>>>(psi, noise, x, c0, partials,
                                               gath, out);
}

// Round 11
// 31.520 us; speedup vs baseline: 1.1204x; 1.0043x over previous
//
#include <hip/hip_runtime.h>
#include <cstdint>
#include <climits>

#define GRID_N 16777216
#define GMAX (GRID_N - 1)
#define N_STEPS 100
#define NCAND (2 * N_STEPS + 1)   // 200 boundary-origin candidates + c0
#define NNODE (2 * N_STEPS)       // boundary-state nodes (t,b), t in [0,100)
#define NLEV 8                    // 2^7 = 128 >= 100 transitions
#define NBLK 2048
#define THREADS 256
#define PER_BLK (GRID_N / 2 / NBLK)   // 4096 float4s = 64KB contiguous per block

#define TERM_FLAG 0x40000000      // terminal: t==100, low 24 bits = final c
#define FALLBACK  (-1)

// nan_to_num(psi, nan=0.0, posinf=1.0, neginf=-1.0)
__device__ __forceinline__ float fixv(float v) {
    if (isnan(v)) return 0.0f;
    if (isinf(v)) return v > 0.0f ? 1.0f : -1.0f;
    return v;
}

// psi0*psi0 + psi1*psi1 in strict f32, no FMA contraction (match host semantics)
__device__ __forceinline__ float raw_prob(float a, float b) {
    return __fadd_rn(__fmul_rn(a, a), __fmul_rn(b, b));
}

// x86 cvttss2si semantics: out-of-range or NaN -> INT_MIN (NOT GPU saturation)
__device__ __forceinline__ int host_f2i(float sf) {
    if (!(sf >= -2147483648.0f && sf < 2147483648.0f)) return INT_MIN;
    return (int)sf;
}

__device__ __forceinline__ int wrap_clip(int c, int shift) {
    int r = (int)((unsigned)c + (unsigned)shift);  // int32 wrapping add (XLA/NumPy)
    if (r < 0) r = 0;
    if (r > GMAX) r = GMAX;
    return r;
}

__device__ __forceinline__ double pair_prob(float4 v) {
    return (double)raw_prob(fixv(v.x), fixv(v.y)) +
           (double)raw_prob(fixv(v.z), fixv(v.w));
}

// candidate position at boundary-origin node tid (exact walk-step fp with s==0)
__device__ __forceinline__ int cand_pos(int tid, const float* noise,
                                        const int* c0p, float DXf, float DTf,
                                        float SQ2DTf) {
    if (tid == NCAND - 1) return *c0p;
    int t = tid >> 1;
    float n = noise[t];
    float move = __fadd_rn(__fmul_rn(0.0f, DTf), __fmul_rn(n, SQ2DTf));
    if (!isfinite(move)) move = 0.0f;
    int shift = host_f2i(__fdiv_rn(move, DXf));
    int b = (tid & 1) ? GMAX : 0;
    return wrap_clip(b, shift);
}

__global__ __launch_bounds__(256) void qpe_sum_kernel(const float4* __restrict__ psi4,
                                                      double* __restrict__ partials) {
    const int tid = threadIdx.x;
    const int bid = blockIdx.x;

    // ---- sum: CONTIGUOUS 64KB slice per block, 8 loads in flight ----
    // (grid = exactly 2048 = full residency; no straggler blocks)
    const int base = bid * PER_BLK + tid;
    double a0 = 0.0, a1 = 0.0, a2 = 0.0, a3 = 0.0;
    double a4 = 0.0, a5 = 0.0, a6 = 0.0, a7 = 0.0;
#pragma unroll
    for (int k = 0; k < PER_BLK / (8 * THREADS); ++k) {   // 2 iterations
        const int i = base + k * 8 * THREADS;
        float4 v0 = psi4[i];
        float4 v1 = psi4[i + THREADS];
        float4 v2 = psi4[i + 2 * THREADS];
        float4 v3 = psi4[i + 3 * THREADS];
        float4 v4 = psi4[i + 4 * THREADS];
        float4 v5 = psi4[i + 5 * THREADS];
        float4 v6 = psi4[i + 6 * THREADS];
        float4 v7 = psi4[i + 7 * THREADS];
        a0 += pair_prob(v0);
        a1 += pair_prob(v1);
        a2 += pair_prob(v2);
        a3 += pair_prob(v3);
        a4 += pair_prob(v4);
        a5 += pair_prob(v5);
        a6 += pair_prob(v6);
        a7 += pair_prob(v7);
    }
    double acc = ((a0 + a1) + (a2 + a3)) + ((a4 + a5) + (a6 + a7));
    __shared__ double sm[256];
    sm[tid] = acc;
    __syncthreads();
    for (int s = 128; s > 0; s >>= 1) {   // fixed-order tree -> deterministic
        if (tid < s) sm[tid] += sm[tid + s];
        __syncthreads();
    }
    if (tid == 0) partials[bid] = sm[0];
}

__global__ __launch_bounds__(256) void qpe_walk_kernel(const float* __restrict__ psi,
                                                       const float* __restrict__ noise,
                                                       const float* __restrict__ x,
                                                       const int* __restrict__ c0p,
                                                       const double* __restrict__ partials,
                                                       float* __restrict__ out) {
    const int tid = threadIdx.x;
    const float DXf    = (float)(20.0 / (double)(GRID_N - 1));
    const float TWODXf = (float)(2.0 * (20.0 / (double)(GRID_N - 1)));
    const float DTf    = 0.01f;
    const float SQ2DTf = (float)0.14142135623730950488;  // np.sqrt(0.02) -> f32

    __shared__ int    cand_c[256];
    __shared__ int    cand_next[256];
    __shared__ int    lift[NLEV][NNODE];
    __shared__ double red[256];
    __shared__ float  norm_sh;

    // ---- phase A: candidate positions; ISSUE scattered psi loads (no pin —
    //      the wait happens after phase B so latency hides under the reduce) ----
    int myc = -1;
    float2 lo = make_float2(0.0f, 0.0f), hi = make_float2(0.0f, 0.0f);
    if (tid < NCAND) {
        myc = cand_pos(tid, noise, c0p, DXf, DTf, SQ2DTf);
        if (myc > 0 && myc < GMAX) {
            lo = *(const float2*)(psi + 2 * myc - 2);  // psi[c-1][0..1]
            hi = *(const float2*)(psi + 2 * myc + 2);  // psi[c+1][0..1]
        }
    }

    // ---- phase B: deterministic fixed-order f64 reduce of partials ----
    double acc = 0.0;
#pragma unroll
    for (int k = 0; k < NBLK / 256; ++k) acc += partials[tid + k * 256];
    red[tid] = acc;
    __syncthreads();
    for (int s = 128; s > 0; s >>= 1) {
        if (tid < s) red[tid] += red[tid + s];
        __syncthreads();
    }
    if (tid == 0) {
        float S = (float)red[0];
        norm_sh = __fadd_rn(__fmul_rn(S, DXf), 1e-8f);
    }
    __syncthreads();
    float norm = norm_sh;

    // pin AFTER phase B: forces the phase-A loads to have completed by here,
    // i.e. their latency overlapped the reduce above.
    if (tid < NCAND) {
        asm volatile("" : "+v"(lo.x), "+v"(lo.y), "+v"(hi.x), "+v"(hi.y));
    }

    // ---- phase C: per-candidate score AND precomputed next position ----
    float s_val = 0.0f;
    int nxt = -2;   // sentinel: no precomputed next
    float w = 0.0f, w2 = 0.0f;   // x[] warm loads (pinned after lift levels)
    if (tid < NCAND && myc > 0 && myc < GMAX) {
        float a0 = fixv(lo.x), b0 = fixv(lo.y);
        float a1 = fixv(hi.x), b1 = fixv(hi.y);
        float p1 = fmaxf(__fdiv_rn(raw_prob(a1, b1), norm), 1e-12f);
        float p0 = fmaxf(__fdiv_rn(raw_prob(a0, b0), norm), 1e-12f);
        s_val = __fdiv_rn(__fsub_rn(logf(p1), logf(p0)), TWODXf);
        // candidate tid is occupied at step (tid>>1)+1 (boundary-origin) or 0 (c0)
        int nidx = (tid == NCAND - 1) ? 0 : (tid >> 1) + 1;
        if (nidx < N_STEPS) {
            float n = noise[nidx];
            // exact walk-step fp sequence with s = s_val:
            float move = __fadd_rn(__fmul_rn(s_val, DTf), __fmul_rn(n, SQ2DTf));
            if (!isfinite(move)) move = 0.0f;
            int shift = host_f2i(__fdiv_rn(move, DXf));
            nxt = wrap_clip(myc, shift);
        }
    }
    cand_c[tid] = (tid < NCAND) ? myc : -1;
    cand_next[tid] = nxt;
    if (tid < NCAND) {
        // issue x[] warms now; wait is deferred past the lift construction
        w  = x[myc < 0 ? 0 : myc];
        w2 = x[(nxt < 0) ? 0 : nxt];
    }
    __syncthreads();

    // ---- phase L0: level-0 transitions for boundary nodes (t,b), n = 2t+b ----
    if (tid < NNODE) {
        int t = tid >> 1;
        int v;
        int c1 = cand_c[tid];                    // landing after step t (exact)
        if (c1 == 0 || c1 == GMAX) {
            int t1 = t + 1;
            v = (t1 == N_STEPS) ? (TERM_FLAG | c1) : ((t1 << 1) | (c1 == GMAX));
        } else if (t + 1 == N_STEPS) {
            v = TERM_FLAG | c1;                  // interior final at t=100
        } else {
            int c2 = cand_next[tid];             // position after step t+1 (exact)
            if (c2 == 0 || c2 == GMAX) {
                int t2 = t + 2;
                v = (t2 == N_STEPS) ? (TERM_FLAG | c2) : ((t2 << 1) | (c2 == GMAX));
            } else if (t + 2 == N_STEPS) {
                v = TERM_FLAG | c2;              // interior final at t=100
            } else {
                v = FALLBACK;                    // interior non-candidate mid-walk
            }
        }
        lift[0][tid] = v;
    }
    __syncthreads();
    // ---- doubling levels: lift[k][n] = lift[k-1] applied twice (saturating) ----
#pragma unroll
    for (int k = 1; k < NLEV; ++k) {
        if (tid < NNODE) {
            int v = lift[k - 1][tid];
            lift[k][tid] = (v >= 0 && v < TERM_FLAG) ? lift[k - 1][v] : v;
        }
        __syncthreads();
    }

    // pin x[] warms here: their latency overlapped the 8 lift levels above
    if (tid < NCAND) {
        asm volatile("" :: "v"(w), "v"(w2));
    }

    if (tid != 0) return;

    // ---- phase D: traverse ----
    int c = cand_c[NCAND - 1];   // == *c0p
    int t = 0;
    bool need_serial = false;

    // step 0 from c0 (interior in this problem; handle boundary anyway)
    int node;
    if (c == 0 || c == GMAX) {
        node = (0 << 1) | (c == GMAX);
    } else {
        int n1 = cand_next[NCAND - 1];           // position after step 0 (exact)
        if (n1 == -2) { need_serial = true; node = -1; }
        else if (n1 == 0 || n1 == GMAX) {
            if (N_STEPS == 1) { out[0] = x[n1]; return; }
            node = (1 << 1) | (n1 == GMAX);
        } else if (N_STEPS == 1) {
            out[0] = x[n1]; return;
        } else {
            need_serial = true; t = 1; c = n1; node = -1;   // rare
        }
    }

    if (!need_serial) {
        // binary lifting: highest level covers 128 >= 100 transitions, so one
        // application usually terminates; descend on fallback-blocked levels.
        for (int guard = 0; guard < 64; ++guard) {
            if (node >= TERM_FLAG) break;
            int applied = 0;
            for (int k = NLEV - 1; k >= 0; --k) {
                int v = lift[k][node];
                if (v != FALLBACK) {
                    node = v;
                    applied = 1;
                    break;
                }
            }
            if (!applied) {                       // lift[0][node] == FALLBACK
                t = node >> 1;
                c = (node & 1) ? GMAX : 0;
                need_serial = true;
                break;
            }
            if (node >= TERM_FLAG) break;
        }
        if (!need_serial && node >= TERM_FLAG) {
            out[0] = x[node & 0xFFFFFF];
            return;
        }
    }

    // ---- serial fallback from exact state (t, c): r6 loop, unconditional ----
    while (t < N_STEPS) {
        if (c <= 0 || c >= GMAX) {
            int j = 2 * t + ((c != 0) ? 1 : 0);
            c = cand_c[j];                        // exact landing (phase A)
            ++t;
        } else {
            float a1v = fixv(psi[2 * (c + 1)]);
            float b1v = fixv(psi[2 * (c + 1) + 1]);
            float a0v = fixv(psi[2 * (c - 1)]);
            float b0v = fixv(psi[2 * (c - 1) + 1]);
            float p1 = fmaxf(__fdiv_rn(raw_prob(a1v, b1v), norm), 1e-12f);
            float p0 = fmaxf(__fdiv_rn(raw_prob(a0v, b0v), norm), 1e-12f);
            float s = __fdiv_rn(__fsub_rn(logf(p1), logf(p0)), TWODXf);
            float n = noise[t];
            float move = __fadd_rn(__fmul_rn(s, DTf), __fmul_rn(n, SQ2DTf));
            if (!isfinite(move)) move = 0.0f;
            int shift = host_f2i(__fdiv_rn(move, DXf));
            c = wrap_clip(c, shift);
            ++t;
        }
    }
    out[0] = x[c];
}

extern "C" void kernel_launch(void* const* d_in, const int* in_sizes, int n_in,
                              void* d_out, int out_size, void* d_ws, size_t ws_size,
                              hipStream_t stream) {
    const float* psi   = (const float*)d_in[0];
    const float* noise = (const float*)d_in[1];
    const float* x     = (const float*)d_in[2];
    const int*   c0    = (const int*)d_in[3];
    float* out = (float*)d_out;

    double* partials = (double*)d_ws;

    qpe_sum_kernel<<<NBLK, THREADS, 0, stream>>>((const float4*)psi, partials);
    qpe_walk_kernel<<<1, THREADS, 0, stream>>>(psi, noise, x, c0, partials, out);
}